// Round 2
// baseline (5729.649 us; speedup 1.0000x reference)
//
#include <hip/hip_runtime.h>
#include <hip/hip_bf16.h>

using bf16 = __hip_bfloat16;
typedef short bf16x8_t __attribute__((ext_vector_type(8)));   // 8 bf16 (4 VGPRs)
typedef float f32x4_t __attribute__((ext_vector_type(4)));

// sizes
#define Bsz 32
#define Ssz 128
#define Tsz 128
#define Esz 256
#define Hsz 512
#define VTsz 16000

__device__ inline float sigm(float x)      { return 1.f / (1.f + __expf(-x)); }
__device__ inline float tanh_fast(float x) { return 1.f - 2.f / (1.f + __expf(2.f * x)); }

__device__ inline unsigned pack2(float x, float y) {
  unsigned short lo = __builtin_bit_cast(unsigned short, __float2bfloat16(x));
  unsigned short hi = __builtin_bit_cast(unsigned short, __float2bfloat16(y));
  return (unsigned)lo | ((unsigned)hi << 16);
}

__device__ inline uint4 f32x8_to_bf16x8(const float* s) {
  float4 a = *(const float4*)s;
  float4 b = *(const float4*)(s + 4);
  uint4 r;
  r.x = pack2(a.x, a.y); r.y = pack2(a.z, a.w);
  r.z = pack2(b.x, b.y); r.w = pack2(b.z, b.w);
  return r;
}

// ---------------------------------------------------------------------------
// Embedding gather + f32->bf16: xs_b[(b*S+s)*E+:] = bf16(emb_src[src[b,s]]).
// One thread per 8-elem chunk. total = 2 * (4096*256/8) = 262144 threads.
// ---------------------------------------------------------------------------
__global__ __launch_bounds__(256) void embed_gather(
    const int* __restrict__ src, const int* __restrict__ tgt,
    const float* __restrict__ es, const float* __restrict__ et,
    bf16* __restrict__ xs_b, bf16* __restrict__ ys_b)
{
  int idx = blockIdx.x * 256 + threadIdx.x;     // 0 .. 262143
  int which = idx >> 17;                        // 131072 chunks per tensor
  int c = idx & 131071;
  int row = c >> 5;                             // 32 chunks per row (E=256)
  int cc = c & 31;
  if (which == 0) {
    int tok = src[row];
    *(uint4*)(xs_b + (size_t)row * Esz + cc * 8) =
        f32x8_to_bf16x8(es + (size_t)tok * Esz + cc * 8);
  } else {
    int tok = tgt[row];
    *(uint4*)(ys_b + (size_t)row * Esz + cc * 8) =
        f32x8_to_bf16x8(et + (size_t)tok * Esz + cc * 8);
  }
}

// ---------------------------------------------------------------------------
// Weight transposes (f32 src -> bf16 dst, k-major for recurrent kernels).
//  encWhh_t[k*1536 + j] = enc_Whh[j*512 + k]                  (512 x 1536)
//  Wcat_t  [k*2048 + j] = j<1536 ? dec_Whh[j*512+k]
//                                 : attn_W[(j-1536)*1024 + k]  (512 x 2048)
//  Wihctx_t[k*1536 + j] = dec_Wih[j*768 + 256 + k]             (512 x 1536)
// total = 512*5120 = 2621440 = 10240*256
// ---------------------------------------------------------------------------
__global__ __launch_bounds__(256) void transpose_w(
    const float* __restrict__ enc_Whh, const float* __restrict__ dec_Whh,
    const float* __restrict__ attn_W,  const float* __restrict__ dec_Wih,
    bf16* __restrict__ encWhh_t, bf16* __restrict__ Wcat_t, bf16* __restrict__ Wihctx_t)
{
  int idx = blockIdx.x * 256 + threadIdx.x;
  const int N1 = 512 * 1536, N2 = 512 * 2048;
  if (idx < N1) {
    int k = idx / 1536, j = idx % 1536;
    encWhh_t[idx] = __float2bfloat16(enc_Whh[(size_t)j * 512 + k]);
  } else if (idx < N1 + N2) {
    int r = idx - N1;
    int k = r / 2048, j = r % 2048;
    float v = (j < 1536) ? dec_Whh[(size_t)j * 512 + k]
                         : attn_W[(size_t)(j - 1536) * 1024 + k];
    Wcat_t[r] = __float2bfloat16(v);
  } else {
    int r = idx - N1 - N2;
    int k = r / 1536, j = r % 1536;
    Wihctx_t[r] = __float2bfloat16(dec_Wih[(size_t)j * 768 + 256 + k]);
  }
}

// ---------------------------------------------------------------------------
// Pack GEMM B-operands f32 -> bf16 (row-major, packed):
//  encWih_b  (1536 x 256)  <- enc_Wih
//  decWihY_b (1536 x 256)  <- dec_Wih[:, :256]   (src ld 768)
//  attnWe_b  (512 x 512)   <- attn_W[:, 512:]    (src ld 1024)
//  fcW_b     (16000 x 512) <- fc_W
// total = 393216 + 393216 + 262144 + 8192000 = 9240576 = 36096*256
// ---------------------------------------------------------------------------
__global__ __launch_bounds__(256) void pack_weights(
    const float* __restrict__ enc_Wih, const float* __restrict__ dec_Wih,
    const float* __restrict__ attn_W,  const float* __restrict__ fc_W,
    bf16* __restrict__ encWih_b, bf16* __restrict__ decWihY_b,
    bf16* __restrict__ attnWe_b, bf16* __restrict__ fcW_b)
{
  int idx = blockIdx.x * 256 + threadIdx.x;
  const int R1 = 1536 * 256, R2 = 1536 * 256, R3 = 512 * 512;
  if (idx < R1) {
    encWih_b[idx] = __float2bfloat16(enc_Wih[idx]);
  } else if (idx < R1 + R2) {
    int r = idx - R1;
    int row = r >> 8, col = r & 255;
    decWihY_b[r] = __float2bfloat16(dec_Wih[(size_t)row * 768 + col]);
  } else if (idx < R1 + R2 + R3) {
    int r = idx - R1 - R2;
    int row = r >> 9, col = r & 511;
    attnWe_b[r] = __float2bfloat16(attn_W[(size_t)row * 1024 + 512 + col]);
  } else {
    int r = idx - R1 - R2 - R3;
    fcW_b[r] = __float2bfloat16(fc_W[r]);
  }
}

// ---------------------------------------------------------------------------
// MFMA GEMM: C[m,n] = sum_k A[m,k]*B[n,k] + bias[n]   (A,B bf16 row-major,
// C fp32). 128x128 tile, BK=64, 256 thr = 4 waves (2x2 of 64x64), 16x16x32.
// Requires: M%128==0 (grid.y), N%128==0 (grid.x), K%64==0, lda/ldb%8==0.
// ---------------------------------------------------------------------------
__global__ __launch_bounds__(256) void gemm_bt(
    const bf16* __restrict__ A, int lda,
    const bf16* __restrict__ B, int ldb,
    float* __restrict__ C, int ldc,
    const float* __restrict__ bias, int K)
{
  __shared__ __align__(16) bf16 As[128 * 64];
  __shared__ __align__(16) bf16 Bs[128 * 64];
  const int tid = threadIdx.x;
  const int m0 = blockIdx.y * 128, n0 = blockIdx.x * 128;
  const int lane = tid & 63, wave = tid >> 6;
  const int wm = (wave >> 1) * 64, wn = (wave & 1) * 64;
  const int fr = lane & 15, quad = lane >> 4;

  f32x4_t acc[4][4];
  const f32x4_t zero = {0.f, 0.f, 0.f, 0.f};
#pragma unroll
  for (int i = 0; i < 4; ++i)
#pragma unroll
    for (int j = 0; j < 4; ++j) acc[i][j] = zero;

  for (int k0 = 0; k0 < K; k0 += 64) {
    __syncthreads();
#pragma unroll
    for (int j = 0; j < 4; ++j) {
      int c = j * 256 + tid;
      int row = c >> 3, cc = c & 7;    // 8 chunks of 16B per 64-col row
      *(uint4*)(As + row * 64 + cc * 8) =
          *(const uint4*)(A + (size_t)(m0 + row) * lda + k0 + cc * 8);
      *(uint4*)(Bs + row * 64 + cc * 8) =
          *(const uint4*)(B + (size_t)(n0 + row) * ldb + k0 + cc * 8);
    }
    __syncthreads();
#pragma unroll
    for (int kk = 0; kk < 64; kk += 32) {
      bf16x8_t af[4], bfr[4];
#pragma unroll
      for (int mt = 0; mt < 4; ++mt)
        af[mt] = *(const bf16x8_t*)(As + (wm + mt * 16 + fr) * 64 + kk + quad * 8);
#pragma unroll
      for (int nt = 0; nt < 4; ++nt)
        bfr[nt] = *(const bf16x8_t*)(Bs + (wn + nt * 16 + fr) * 64 + kk + quad * 8);
#pragma unroll
      for (int mt = 0; mt < 4; ++mt)
#pragma unroll
        for (int nt = 0; nt < 4; ++nt)
          acc[mt][nt] = __builtin_amdgcn_mfma_f32_16x16x32_bf16(
              af[mt], bfr[nt], acc[mt][nt], 0, 0, 0);
    }
  }

#pragma unroll
  for (int mt = 0; mt < 4; ++mt) {
#pragma unroll
    for (int nt = 0; nt < 4; ++nt) {
      int n = n0 + wn + nt * 16 + fr;
      float bv = bias[n];
#pragma unroll
      for (int r = 0; r < 4; ++r) {
        int m = m0 + wm + mt * 16 + quad * 4 + r;
        C[(size_t)m * ldc + n] = acc[mt][nt][r] + bv;
      }
    }
  }
}

// ---------------------------------------------------------------------------
// Encoder recurrent step. grid = 256 blocks (32 b x 8 i-tiles of 64).
// block = 256 thr (64 i-lanes x 4 k-groups). h kept fp32.
// ---------------------------------------------------------------------------
__global__ __launch_bounds__(256) void enc_step(
    const float* __restrict__ enc_gi, const bf16* __restrict__ Wt,
    const float* __restrict__ bhh, float* __restrict__ enc_out,
    bf16* __restrict__ enc_out_b, int t)
{
  __shared__ float hs[Hsz];
  __shared__ float ps[4][3][64];
  const int b = blockIdx.x >> 3, it = blockIdx.x & 7;
  const int tid = threadIdx.x, il = tid & 63, kg = tid >> 6;

  if (t == 0) {
    for (int i = tid; i < Hsz; i += 256) hs[i] = 0.f;
  } else {
    const float* hsrc = enc_out + ((size_t)b * Ssz + (t - 1)) * Hsz;
    for (int i = tid; i < Hsz; i += 256) hs[i] = hsrc[i];
  }
  __syncthreads();

  const int i = it * 64 + il;
  float pr = 0.f, pz = 0.f, pn = 0.f;
  for (int k = kg * 128; k < kg * 128 + 128; ++k) {
    const float hv = hs[k];
    const bf16* w = Wt + (size_t)k * 1536;
    pr += hv * (float)w[i];
    pz += hv * (float)w[Hsz + i];
    pn += hv * (float)w[2 * Hsz + i];
  }
  ps[kg][0][il] = pr; ps[kg][1][il] = pz; ps[kg][2][il] = pn;
  __syncthreads();

  if (tid < 64) {
    float ghr = ps[0][0][il] + ps[1][0][il] + ps[2][0][il] + ps[3][0][il] + bhh[i];
    float ghz = ps[0][1][il] + ps[1][1][il] + ps[2][1][il] + ps[3][1][il] + bhh[Hsz + i];
    float ghn = ps[0][2][il] + ps[1][2][il] + ps[2][2][il] + ps[3][2][il] + bhh[2 * Hsz + i];
    const float* gi = enc_gi + ((size_t)b * Ssz + t) * 1536;
    const float r = sigm(gi[i] + ghr);
    const float z = sigm(gi[Hsz + i] + ghz);
    const float n = tanh_fast(gi[2 * Hsz + i] + r * ghn);
    const float h2 = (1.f - z) * n + z * hs[i];
    const size_t o = ((size_t)b * Ssz + t) * Hsz + i;
    enc_out[o] = h2;
    enc_out_b[o] = __float2bfloat16(h2);
  }
}

// ---------------------------------------------------------------------------
// Decoder step kernel 1: gh = h@Whh^T + bhh  and  hW = h@Wh^T  (combined:
// j in [0,2048): first 1536 -> gh, last 512 -> hW). grid = 1024 (32b x 32jt).
// ---------------------------------------------------------------------------
__global__ __launch_bounds__(256) void dec_k1(
    const float* __restrict__ enc_out, const float* __restrict__ dec_seq,
    const bf16* __restrict__ Wcat_t, const float* __restrict__ dbhh,
    float* __restrict__ gh_ws, float* __restrict__ hW_ws, int t)
{
  __shared__ float hs[Hsz];
  __shared__ float ps[4][64];
  const int b = blockIdx.x >> 5, jt = blockIdx.x & 31;
  const int tid = threadIdx.x, il = tid & 63, kg = tid >> 6;

  const float* hsrc = (t == 0) ? (enc_out + ((size_t)b * Ssz + (Ssz - 1)) * Hsz)
                               : (dec_seq + ((size_t)b * Tsz + (t - 1)) * Hsz);
  for (int i = tid; i < Hsz; i += 256) hs[i] = hsrc[i];
  __syncthreads();

  const int j = jt * 64 + il;
  float p = 0.f;
  for (int k = kg * 128; k < kg * 128 + 128; ++k)
    p += hs[k] * (float)Wcat_t[(size_t)k * 2048 + j];
  ps[kg][il] = p;
  __syncthreads();

  if (tid < 64) {
    float s = ps[0][il] + ps[1][il] + ps[2][il] + ps[3][il];
    if (j < 1536) gh_ws[b * 1536 + j] = s + dbhh[j];
    else          hW_ws[b * Hsz + (j - 1536)] = s;
  }
}

// ---------------------------------------------------------------------------
// Decoder step kernel 2: scores -> softmax -> ctx. grid = 32 (one per b),
// 512 threads (8 waves; wave handles one s at a time).
// ---------------------------------------------------------------------------
__global__ __launch_bounds__(512) void dec_k2(
    const float* __restrict__ hW_ws, const float* __restrict__ enc_proj,
    const float* __restrict__ enc_out, const float* __restrict__ attn_v,
    float* __restrict__ ctx_ws)
{
  __shared__ float hw[Hsz], vv[Hsz], sc[Ssz], red[2], red2[2];
  const int b = blockIdx.x, tid = threadIdx.x;
  for (int i = tid; i < Hsz; i += 512) { hw[i] = hW_ws[b * Hsz + i]; vv[i] = attn_v[i]; }
  __syncthreads();

  const int wv = tid >> 6, lane = tid & 63;
  for (int s = wv; s < Ssz; s += 8) {
    const float* ep = enc_proj + ((size_t)b * Ssz + s) * Hsz;
    float pp = 0.f;
#pragma unroll
    for (int q = 0; q < 8; ++q) {
      int i = q * 64 + lane;
      pp += tanh_fast(hw[i] + ep[i]) * vv[i];
    }
#pragma unroll
    for (int off = 32; off; off >>= 1) pp += __shfl_down(pp, off);
    if (lane == 0) sc[s] = pp;
  }
  __syncthreads();

  if (tid < 128) {
    float v = sc[tid];
#pragma unroll
    for (int off = 32; off; off >>= 1) v = fmaxf(v, __shfl_down(v, off));
    if (lane == 0) red[tid >> 6] = v;
  }
  __syncthreads();
  const float mx = fmaxf(red[0], red[1]);
  if (tid < 128) {
    float e = __expf(sc[tid] - mx);
    sc[tid] = e;
    float v = e;
#pragma unroll
    for (int off = 32; off; off >>= 1) v += __shfl_down(v, off);
    if (lane == 0) red2[tid >> 6] = v;
  }
  __syncthreads();
  const float inv = 1.f / (red2[0] + red2[1]);

  for (int i = tid; i < Hsz; i += 512) {
    float a = 0.f;
    for (int s = 0; s < Ssz; ++s) a += sc[s] * enc_out[((size_t)b * Ssz + s) * Hsz + i];
    ctx_ws[b * Hsz + i] = a * inv;
  }
}

// ---------------------------------------------------------------------------
// Decoder step kernel 3: gi_ctx = ctx@Wih_ctx^T; gates; h2. grid = 256.
// ---------------------------------------------------------------------------
__global__ __launch_bounds__(256) void dec_k3(
    const float* __restrict__ ctx_ws, const bf16* __restrict__ Wihctx_t,
    const float* __restrict__ dec_gi_y, const float* __restrict__ gh_ws,
    const float* __restrict__ enc_out, float* __restrict__ dec_seq,
    bf16* __restrict__ dec_out_b, int t)
{
  __shared__ float cs[Hsz];
  __shared__ float ps[4][3][64];
  const int b = blockIdx.x >> 3, it = blockIdx.x & 7;
  const int tid = threadIdx.x, il = tid & 63, kg = tid >> 6;

  for (int i = tid; i < Hsz; i += 256) cs[i] = ctx_ws[b * Hsz + i];
  __syncthreads();

  const int i = it * 64 + il;
  float pr = 0.f, pz = 0.f, pn = 0.f;
  for (int k = kg * 128; k < kg * 128 + 128; ++k) {
    const float c = cs[k];
    const bf16* w = Wihctx_t + (size_t)k * 1536;
    pr += c * (float)w[i];
    pz += c * (float)w[Hsz + i];
    pn += c * (float)w[2 * Hsz + i];
  }
  ps[kg][0][il] = pr; ps[kg][1][il] = pz; ps[kg][2][il] = pn;
  __syncthreads();

  if (tid < 64) {
    const float* giy = dec_gi_y + ((size_t)b * Tsz + t) * 1536;
    const float* gh  = gh_ws + b * 1536;
    float gir = giy[i]           + ps[0][0][il] + ps[1][0][il] + ps[2][0][il] + ps[3][0][il];
    float giz = giy[Hsz + i]     + ps[0][1][il] + ps[1][1][il] + ps[2][1][il] + ps[3][1][il];
    float gin = giy[2 * Hsz + i] + ps[0][2][il] + ps[1][2][il] + ps[2][2][il] + ps[3][2][il];
    float ghr = gh[i], ghz = gh[Hsz + i], ghn = gh[2 * Hsz + i];
    const float* hsrc = (t == 0) ? (enc_out + ((size_t)b * Ssz + (Ssz - 1)) * Hsz)
                                 : (dec_seq + ((size_t)b * Tsz + (t - 1)) * Hsz);
    float hp = hsrc[i];
    const float r = sigm(gir + ghr);
    const float z = sigm(giz + ghz);
    const float n = tanh_fast(gin + r * ghn);
    const float h2 = (1.f - z) * n + z * hp;
    const size_t o = ((size_t)b * Tsz + t) * Hsz + i;
    dec_seq[o] = h2;
    dec_out_b[o] = __float2bfloat16(h2);
  }
}

// ---------------------------------------------------------------------------
extern "C" void kernel_launch(void* const* d_in, const int* in_sizes, int n_in,
                              void* d_out, int out_size, void* d_ws, size_t ws_size,
                              hipStream_t stream) {
  const int*   src      = (const int*)d_in[0];
  const int*   tgt      = (const int*)d_in[1];
  const float* emb_src  = (const float*)d_in[2];
  const float* emb_tgt  = (const float*)d_in[3];
  const float* enc_Wih  = (const float*)d_in[4];
  const float* enc_Whh  = (const float*)d_in[5];
  const float* enc_bih  = (const float*)d_in[6];
  const float* enc_bhh  = (const float*)d_in[7];
  const float* dec_Wih  = (const float*)d_in[8];
  const float* dec_Whh  = (const float*)d_in[9];
  const float* dec_bih  = (const float*)d_in[10];
  const float* dec_bhh  = (const float*)d_in[11];
  const float* attn_W   = (const float*)d_in[12];
  const float* attn_b   = (const float*)d_in[13];
  const float* attn_v   = (const float*)d_in[14];
  const float* fc_W     = (const float*)d_in[15];
  const float* fc_b     = (const float*)d_in[16];
  float* out = (float*)d_out;

  char* p = (char*)d_ws;
  auto alloc = [&](size_t n) { char* r = p; p += (n + 255) & ~(size_t)255; return r; };
  float* enc_gi    = (float*)alloc(4096ull * 1536 * 4);  // (B,S,3H) x@Wih^T+bih
  float* dec_gi_y  = (float*)alloc(4096ull * 1536 * 4);  // (B,T,3H) y@WihY^T+bih
  float* enc_out   = (float*)alloc(4096ull * 512 * 4);   // (B,S,H) fp32 h
  float* enc_proj  = (float*)alloc(4096ull * 512 * 4);   // (B,S,H)
  float* dec_seq   = (float*)alloc(4096ull * 512 * 4);   // (B,T,H) fp32 h
  bf16*  enc_out_b = (bf16*)alloc(4096ull * 512 * 2);
  bf16*  dec_out_b = (bf16*)alloc(4096ull * 512 * 2);
  bf16*  xs_b      = (bf16*)alloc(4096ull * 256 * 2);
  bf16*  ys_b      = (bf16*)alloc(4096ull * 256 * 2);
  bf16*  encWhh_t  = (bf16*)alloc(512ull * 1536 * 2);
  bf16*  Wcat_t    = (bf16*)alloc(512ull * 2048 * 2);
  bf16*  Wihctx_t  = (bf16*)alloc(512ull * 1536 * 2);
  bf16*  encWih_b  = (bf16*)alloc(1536ull * 256 * 2);
  bf16*  decWihY_b = (bf16*)alloc(1536ull * 256 * 2);
  bf16*  attnWe_b  = (bf16*)alloc(512ull * 512 * 2);
  bf16*  fcW_b     = (bf16*)alloc(16000ull * 512 * 2);
  float* gh_ws     = (float*)alloc(32ull * 1536 * 4);
  float* hW_ws     = (float*)alloc(32ull * 512 * 4);
  float* ctx_ws    = (float*)alloc(32ull * 512 * 4);

  embed_gather<<<1024, 256, 0, stream>>>(src, tgt, emb_src, emb_tgt, xs_b, ys_b);
  transpose_w<<<10240, 256, 0, stream>>>(enc_Whh, dec_Whh, attn_W, dec_Wih,
                                         encWhh_t, Wcat_t, Wihctx_t);
  pack_weights<<<36096, 256, 0, stream>>>(enc_Wih, dec_Wih, attn_W, fc_W,
                                          encWih_b, decWihY_b, attnWe_b, fcW_b);

  // enc_gi = xs @ enc_Wih^T + bih   (M=4096, N=1536, K=256)
  gemm_bt<<<dim3(12, 32), 256, 0, stream>>>(xs_b, 256, encWih_b, 256,
                                            enc_gi, 1536, enc_bih, 256);
  // dec_gi_y = ys @ dec_Wih[:, :E]^T + bih
  gemm_bt<<<dim3(12, 32), 256, 0, stream>>>(ys_b, 256, decWihY_b, 256,
                                            dec_gi_y, 1536, dec_bih, 256);

  for (int t = 0; t < Ssz; ++t)
    enc_step<<<256, 256, 0, stream>>>(enc_gi, encWhh_t, enc_bhh, enc_out, enc_out_b, t);

  // enc_proj = enc_out @ We^T + attn_b  (M=4096, N=512, K=512)
  gemm_bt<<<dim3(4, 32), 256, 0, stream>>>(enc_out_b, 512, attnWe_b, 512,
                                           enc_proj, 512, attn_b, 512);

  for (int t = 0; t < Tsz; ++t) {
    dec_k1<<<1024, 256, 0, stream>>>(enc_out, dec_seq, Wcat_t, dec_bhh, gh_ws, hW_ws, t);
    dec_k2<<<32, 512, 0, stream>>>(hW_ws, enc_proj, enc_out, attn_v, ctx_ws);
    dec_k3<<<256, 256, 0, stream>>>(ctx_ws, Wihctx_t, dec_gi_y, gh_ws, enc_out,
                                    dec_seq, dec_out_b, t);
  }

  // logits = dec_out @ fc_W^T + fc_b  (M=4096, N=16000, K=512) -> fp32 out
  gemm_bt<<<dim3(125, 32), 256, 0, stream>>>(dec_out_b, 512, fcW_b, 512,
                                             out, VTsz, fc_b, 512);
}